// Round 2
// baseline (620.319 us; speedup 1.0000x reference)
//
#include <hip/hip_runtime.h>

#define EPS 1e-5f

// Problem dims (hardcoded from setup_inputs)
// feat (2,128,128,128), guide (2,3,256,256), out (2,128,256,256)
// E=32 encoder channels, K=3, k2=9

__global__ __launch_bounds__(256) void k_conv_guide(
    const float* __restrict__ guide, const float* __restrict__ w1,
    float* __restrict__ x1)
{
    unsigned idx = blockIdx.x * 256u + threadIdx.x;   // over B*H2*W2 = 131072
    int x = idx & 255, y = (idx >> 8) & 255, b = idx >> 16;
    float t[3][9];
#pragma unroll
    for (int c = 0; c < 3; ++c)
#pragma unroll
        for (int ky = 0; ky < 3; ++ky)
#pragma unroll
            for (int kx = 0; kx < 3; ++kx) {
                int yy = y + ky - 1, xx = x + kx - 1;
                bool ok = (yy >= 0 && yy < 256 && xx >= 0 && xx < 256);
                t[c][ky * 3 + kx] = ok ? guide[((b * 3 + c) * 256 + yy) * 256 + xx] : 0.f;
            }
#pragma unroll 4
    for (int e = 0; e < 32; ++e) {
        float acc = 0.f;
#pragma unroll
        for (int c = 0; c < 3; ++c)
#pragma unroll
            for (int k = 0; k < 9; ++k)
                acc += t[c][k] * w1[e * 27 + c * 9 + k];
        x1[((b * 32 + e) * 256 + y) * 256 + x] = acc;
    }
}

// Per-channel batch stats over (B,H2,W2); writes a = gamma*rsqrt(var+eps),
// b = beta - mean*a   into ab[c], ab[32+c]. One block per channel.
__global__ __launch_bounds__(256) void k_stats(
    const float* __restrict__ xin, const float* __restrict__ gamma,
    const float* __restrict__ beta, float* __restrict__ ab)
{
    int c = blockIdx.x, tid = threadIdx.x;
    float s = 0.f, ss = 0.f;
    for (int b = 0; b < 2; ++b) {
        const float* p = xin + (size_t)(b * 32 + c) * 65536;
        for (int i = tid; i < 65536; i += 256) {
            float v = p[i];
            s += v; ss += v * v;
        }
    }
    __shared__ float rs[256], rss[256];
    rs[tid] = s; rss[tid] = ss;
    __syncthreads();
    for (int o = 128; o > 0; o >>= 1) {
        if (tid < o) { rs[tid] += rs[tid + o]; rss[tid] += rss[tid + o]; }
        __syncthreads();
    }
    if (tid == 0) {
        const float n = 131072.f;
        float mean = rs[0] / n;
        float var = rss[0] / n - mean * mean;
        float a = gamma[c] * rsqrtf(var + EPS);
        ab[c] = a;
        ab[32 + c] = beta[c] - mean * a;
    }
}

// conv3x3 32->32 on bn+relu(x1); writes raw conv output x2 (pre-BN)
__global__ __launch_bounds__(256) void k_conv2(
    const float* __restrict__ x1, const float* __restrict__ ab1,
    const float* __restrict__ w2, float* __restrict__ x2)
{
    unsigned idx = blockIdx.x * 256u + threadIdx.x;
    int x = idx & 255, y = (idx >> 8) & 255, b = idx >> 16;
    float acc[32];
#pragma unroll
    for (int e = 0; e < 32; ++e) acc[e] = 0.f;
#pragma unroll 1
    for (int c = 0; c < 32; ++c) {
        float a = ab1[c], bb = ab1[32 + c];
        float t[9];
#pragma unroll
        for (int ky = 0; ky < 3; ++ky)
#pragma unroll
            for (int kx = 0; kx < 3; ++kx) {
                int yy = y + ky - 1, xx = x + kx - 1;
                bool ok = (yy >= 0 && yy < 256 && xx >= 0 && xx < 256);
                float v = ok ? x1[((b * 32 + c) * 256 + yy) * 256 + xx] : 0.f;
                v = a * v + bb;
                v = v > 0.f ? v : 0.f;
                t[ky * 3 + kx] = ok ? v : 0.f;
            }
#pragma unroll
        for (int e = 0; e < 32; ++e)
#pragma unroll
            for (int k = 0; k < 9; ++k)
                acc[e] += t[k] * w2[(e * 32 + c) * 9 + k];
    }
#pragma unroll
    for (int e = 0; e < 32; ++e)
        x2[((b * 32 + e) * 256 + y) * 256 + x] = acc[e];
}

// 1x1 proj of feat (at LOWRES, since feat_up is 2x2 replicated) + ReLU
__global__ __launch_bounds__(256) void k_proj(
    const float* __restrict__ feat, const float* __restrict__ pw,
    float* __restrict__ fs)
{
    unsigned idx = blockIdx.x * 256u + threadIdx.x;  // over B*H*W = 32768
    int x = idx & 127, y = (idx >> 7) & 127, b = idx >> 14;
    float acc[32];
#pragma unroll
    for (int e = 0; e < 32; ++e) acc[e] = 0.f;
#pragma unroll 1
    for (int c = 0; c < 128; ++c) {
        float v = feat[((b * 128 + c) * 128 + y) * 128 + x];
#pragma unroll
        for (int e = 0; e < 32; ++e)
            acc[e] += v * pw[e * 128 + c];
    }
#pragma unroll
    for (int e = 0; e < 32; ++e) {
        float v = acc[e];
        fs[((b * 32 + e) * 128 + y) * 128 + x] = v > 0.f ? v : 0.f;
    }
}

// kernel-prediction head: conv3x3 (64->32) on [bnrelu(x2), fs-upsampled],
// then ReLU, then 1x1 -> 9 + bias, softmax over the 9. Writes kern (B,9,H2,W2).
__global__ __launch_bounds__(256) void k_kern(
    const float* __restrict__ x2, const float* __restrict__ ab2,
    const float* __restrict__ fs, const float* __restrict__ kw1,
    const float* __restrict__ kw2, const float* __restrict__ kb2,
    float* __restrict__ kern)
{
    unsigned idx = blockIdx.x * 256u + threadIdx.x;
    int x = idx & 255, y = (idx >> 8) & 255, b = idx >> 16;
    float acc[32];
#pragma unroll
    for (int e = 0; e < 32; ++e) acc[e] = 0.f;

    // g channels (0..31): bn+relu of x2
#pragma unroll 1
    for (int c = 0; c < 32; ++c) {
        float a = ab2[c], bb = ab2[32 + c];
        float t[9];
#pragma unroll
        for (int ky = 0; ky < 3; ++ky)
#pragma unroll
            for (int kx = 0; kx < 3; ++kx) {
                int yy = y + ky - 1, xx = x + kx - 1;
                bool ok = (yy >= 0 && yy < 256 && xx >= 0 && xx < 256);
                float v = ok ? x2[((b * 32 + c) * 256 + yy) * 256 + xx] : 0.f;
                v = a * v + bb;
                v = v > 0.f ? v : 0.f;
                t[ky * 3 + kx] = ok ? v : 0.f;
            }
#pragma unroll
        for (int e = 0; e < 32; ++e)
#pragma unroll
            for (int k = 0; k < 9; ++k)
                acc[e] += t[k] * kw1[(e * 64 + c) * 9 + k];
    }
    // f channels (32..63): fs replicated 2x2 (already ReLU'd)
#pragma unroll 1
    for (int c = 0; c < 32; ++c) {
        float t[9];
#pragma unroll
        for (int ky = 0; ky < 3; ++ky)
#pragma unroll
            for (int kx = 0; kx < 3; ++kx) {
                int yy = y + ky - 1, xx = x + kx - 1;
                bool ok = (yy >= 0 && yy < 256 && xx >= 0 && xx < 256);
                t[ky * 3 + kx] = ok ? fs[((b * 32 + c) * 128 + (yy >> 1)) * 128 + (xx >> 1)] : 0.f;
            }
#pragma unroll
        for (int e = 0; e < 32; ++e)
#pragma unroll
            for (int k = 0; k < 9; ++k)
                acc[e] += t[k] * kw1[(e * 64 + 32 + c) * 9 + k];
    }
    // ReLU -> 1x1 head -> softmax   (the ReLU was the round-1 bug)
    float z[9];
#pragma unroll
    for (int i = 0; i < 9; ++i) z[i] = kb2[i];
#pragma unroll
    for (int e = 0; e < 32; ++e) {
        float ae = fmaxf(acc[e], 0.f);
#pragma unroll
        for (int i = 0; i < 9; ++i)
            z[i] += ae * kw2[i * 32 + e];
    }
    float m = z[0];
#pragma unroll
    for (int i = 1; i < 9; ++i) m = fmaxf(m, z[i]);
    float sum = 0.f;
#pragma unroll
    for (int i = 0; i < 9; ++i) { z[i] = expf(z[i] - m); sum += z[i]; }
    float inv = 1.f / sum;
#pragma unroll
    for (int i = 0; i < 9; ++i)
        kern[((b * 9 + i) * 256 + y) * 256 + x] = z[i] * inv;
}

// CARAFE reassembly. Thread owns one lowres pixel (2x2 output block) and a
// 16-channel slice; kern (36 vals) stays in registers across the c-loop.
__global__ __launch_bounds__(256) void k_out(
    const float* __restrict__ feat, const float* __restrict__ kern,
    float* __restrict__ out)
{
    unsigned idx = blockIdx.x * 256u + threadIdx.x;  // over B*8*H*W = 262144
    int x = idx & 127, y = (idx >> 7) & 127, cc = (idx >> 14) & 7, b = idx >> 17;

    float k4[2][2][9];
#pragma unroll
    for (int i = 0; i < 9; ++i)
#pragma unroll
        for (int ry = 0; ry < 2; ++ry) {
            const float2 kv = *reinterpret_cast<const float2*>(
                &kern[(((b * 9 + i) * 256) + (2 * y + ry)) * 256 + 2 * x]);
            k4[ry][0][i] = kv.x;
            k4[ry][1][i] = kv.y;
        }

    // jmap[r][d] = lowres offset index (0,1,2 -> row y-1,y,y+1) for output
    // parity r and tap d; validity exactly matches the zero-padded f3 load.
    const int jmap[2][3] = { {0, 1, 1}, {1, 1, 2} };

#pragma unroll 1
    for (int j = 0; j < 16; ++j) {
        int c = cc * 16 + j;
        float f3[3][3];
#pragma unroll
        for (int jy = 0; jy < 3; ++jy)
#pragma unroll
            for (int jx = 0; jx < 3; ++jx) {
                int yl = y + jy - 1, xl = x + jx - 1;
                bool ok = (yl >= 0 && yl < 128 && xl >= 0 && xl < 128);
                f3[jy][jx] = ok ? feat[((b * 128 + c) * 128 + yl) * 128 + xl] : 0.f;
            }
        float a[2][2] = { {0.f, 0.f}, {0.f, 0.f} };
#pragma unroll
        for (int ry = 0; ry < 2; ++ry)
#pragma unroll
            for (int dy = 0; dy < 3; ++dy)
#pragma unroll
                for (int rx = 0; rx < 2; ++rx)
#pragma unroll
                    for (int dx = 0; dx < 3; ++dx)
                        a[ry][rx] += k4[ry][rx][dy * 3 + dx] * f3[jmap[ry][dy]][jmap[rx][dx]];
#pragma unroll
        for (int ry = 0; ry < 2; ++ry) {
            float2 o; o.x = a[ry][0]; o.y = a[ry][1];
            *reinterpret_cast<float2*>(
                &out[((b * 128 + c) * 256 + (2 * y + ry)) * 256 + 2 * x]) = o;
        }
    }
}

extern "C" void kernel_launch(void* const* d_in, const int* in_sizes, int n_in,
                              void* d_out, int out_size, void* d_ws, size_t ws_size,
                              hipStream_t stream)
{
    const float* feat  = (const float*)d_in[0];
    const float* guide = (const float*)d_in[1];
    const float* g_w1  = (const float*)d_in[2];
    const float* g_g1  = (const float*)d_in[3];
    const float* g_b1  = (const float*)d_in[4];
    const float* g_w2  = (const float*)d_in[5];
    const float* g_g2  = (const float*)d_in[6];
    const float* g_b2  = (const float*)d_in[7];
    const float* p_w   = (const float*)d_in[8];
    const float* k_w1  = (const float*)d_in[9];
    const float* k_w2  = (const float*)d_in[10];
    const float* k_b2  = (const float*)d_in[11];

    float* out = (float*)d_out;

    // Big intermediates live inside d_out (64 MB), dead before k_out writes it:
    //   x1: [0 .. 16MB), x2: [16MB .. 32MB)
    float* x1 = out;                  // 2*32*256*256 = 4,194,304 floats
    float* x2 = out + 4194304;        // 4,194,304 floats

    // Workspace: fs (2,32,128,128) + kern (2,9,256,256) + 2x stats
    float* fs   = (float*)d_ws;       // 2,097,152 floats
    float* kern = fs + 2097152;       // 1,179,648 floats
    float* ab1  = kern + 1179648;     // 64 floats
    float* ab2  = ab1 + 64;           // 64 floats

    k_conv_guide<<<512, 256, 0, stream>>>(guide, g_w1, x1);
    k_stats<<<32, 256, 0, stream>>>(x1, g_g1, g_b1, ab1);
    k_conv2<<<512, 256, 0, stream>>>(x1, ab1, g_w2, x2);
    k_stats<<<32, 256, 0, stream>>>(x2, g_g2, g_b2, ab2);
    k_proj<<<128, 256, 0, stream>>>(feat, p_w, fs);
    k_kern<<<512, 256, 0, stream>>>(x2, ab2, fs, k_w1, k_w2, k_b2, kern);
    k_out<<<1024, 256, 0, stream>>>(feat, kern, out);
}